// Round 7
// baseline (705.442 us; speedup 1.0000x reference)
//
#include <hip/hip_runtime.h>

// AblationDecoder: B=8, N=50000, DIM=3, C_DIM=64, TASK_DIM=512, H=64, NB=5, OUT=12
// R7 = R6 with the rb() buffer-overwrite hazard fixed: next-cond prefetch moved
// AFTER all 4 tiles (R4's proven schedule), LDS-resident weights kept.
#define B_    8
#define N_    50000
#define NB_   5
#define OUT_  12
#define THREADS 512
#define GRID   768
#define TILES_ 4
#define NGROUPS 6250          // (8*50000/16)/4 four-tile groups
#define PRIMARY 6144          // GRID * 8 waves
#define EXTRA  (NGROUPS - PRIMARY)   // 106

// LDS layout (bytes)
#define WL_OFF   0            // 7808 chunks * 16B = 124928 (15 stages + fco)
#define TPL_OFF  124928       // tp''[8][5][64] f32 = 10240
#define B0L_OFF  135168       // blk0_b[5][64] f32 = 1280
#define B14_OFF  136448       // blk1_b[4][64] f32 = 256
#define FPW_OFF  136704       // fc_p_W [3][64] f32 = 768
#define SMEM_BYTES 137472

typedef _Float16 half8  __attribute__((ext_vector_type(8)));
typedef __fp16   fp16x2 __attribute__((ext_vector_type(2)));   // cvt_pkrtz return type
typedef float   floatx4 __attribute__((ext_vector_type(4)));

__device__ __forceinline__ half8 ldl8(const _Float16* p) {
    union { uint4 u; half8 h; } x;
    x.u = *(const uint4*)p;
    return x.h;
}

// relu + pack 8 f32 (two D-layout accs) -> B fragment, via v_cvt_pkrtz
__device__ __forceinline__ half8 packB(floatx4 a, floatx4 b) {
    union { fp16x2 h2[4]; half8 h8; } u;
    u.h2[0] = __builtin_amdgcn_cvt_pkrtz(fmaxf(a[0], 0.f), fmaxf(a[1], 0.f));
    u.h2[1] = __builtin_amdgcn_cvt_pkrtz(fmaxf(a[2], 0.f), fmaxf(a[3], 0.f));
    u.h2[2] = __builtin_amdgcn_cvt_pkrtz(fmaxf(b[0], 0.f), fmaxf(b[1], 0.f));
    u.h2[3] = __builtin_amdgcn_cvt_pkrtz(fmaxf(b[2], 0.f), fmaxf(b[3], 0.f));
    return u.h8;
}

// load one stage's 8 A-fragments from LDS (frag idx = 2T+h)
__device__ __forceinline__ void loadL8(half8 (&A)[8], const _Float16* wl, int stage, int lane) {
    const _Float16* b = wl + (size_t)stage * 512 * 8;
    #pragma unroll
    for (int T = 0; T < 4; ++T)
        #pragma unroll
        for (int h = 0; h < 2; ++h)
            A[2 * T + h] = ldl8(b + (size_t)(T * 128 + h * 64 + lane) * 8);
}

// ---------------------------------------------------------------------------
// Pre-kernel A: blocks 0..31 build f16 A-fragment weights (single copy);
// blocks 32..111 compute task-feature projection partials.
// ws chunk layout (16B chunks): cidx = stage*512 + T*128 + h*64 + q*16 + m15
//   stage: cond_i=i, blk0_i=5+i, blk1_i=10+i, fco=15 (chunks 7680..7807 real)
//   halves j: cond: k=32h+8q+j (natural-k c); blk0/blk1/fco: f=32h+16*(j>>2)+4q+(j&3)
// ---------------------------------------------------------------------------
__global__ void prep_kernel(const float* __restrict__ fc_c_W,
                            const float* __restrict__ blk0_W,
                            const float* __restrict__ blk1_W,
                            const float* __restrict__ fc_out_W,
                            const float* __restrict__ tf,
                            _Float16* __restrict__ ws_w,
                            float* __restrict__ partials) {
    int bid = blockIdx.x, tid = threadIdx.x;
    if (bid < 32) {
        int u = bid * 256 + tid;          // 0..8191
        if (u < 7680) {
            int m15 = u & 15, q = (u >> 4) & 3, h = (u >> 6) & 1, T = (u >> 7) & 3;
            int mi = u >> 9;              // 0..14
            int mat = mi / 5, i = mi % 5;
            int n = T * 16 + m15;
            _Float16 out[8];
            #pragma unroll
            for (int j = 0; j < 8; ++j) {
                float v;
                if (mat == 0) {
                    int k = 32 * h + 8 * q + j;
                    v = fc_c_W[((size_t)i * 576 + k) * 64 + n];
                } else {
                    int f = 32 * h + 16 * (j >> 2) + 4 * q + (j & 3);
                    const float* W = (mat == 1) ? blk0_W : blk1_W;
                    v = W[((size_t)i * 64 + f) * 64 + n];
                }
                out[j] = (_Float16)v;
            }
            *(uint4*)(ws_w + (size_t)u * 8) = *(uint4*)out;
        } else {
            int e = u - 7680;             // 0..511 (only 0..127 meaningful)
            _Float16 out[8] = {};
            if (e < 128) {
                int m15 = e & 15, q = (e >> 4) & 3, h = (e >> 6) & 1;
                #pragma unroll
                for (int j = 0; j < 8; ++j) {
                    int f = 32 * h + 16 * (j >> 2) + 4 * q + (j & 3);
                    out[j] = (m15 < OUT_) ? (_Float16)fc_out_W[f * OUT_ + m15] : (_Float16)0.f;
                }
            }
            *(uint4*)(ws_w + (size_t)u * 8) = *(uint4*)out;
        }
    } else {
        int idx2 = bid - 32;              // 0..79
        int b = idx2 / 10, rem = idx2 % 10, i = rem >> 1, hf = rem & 1;
        int g = tid >> 6, j = tid & 63;
        const float* W  = fc_c_W + ((size_t)i * 576 + 64) * 64;
        const float* tb = tf + b * 512;
        int t0 = hf * 256 + g * 64;
        float acc = 0.f;
        #pragma unroll 8
        for (int t = 0; t < 64; ++t)
            acc += tb[t0 + t] * W[(size_t)(t0 + t) * 64 + j];
        partials[(((b * 5 + i) << 3) + (hf * 4 + g)) * 64 + j] = acc;
    }
}

// Pre-kernel B: tp''[b][i] = Σ partials + fc_c_b[i] + (i==0 ? fc_p_b : blk1_b[i-1])
__global__ void finalize_tp(const float* __restrict__ partials,
                            const float* __restrict__ fc_c_b,
                            const float* __restrict__ fc_p_b,
                            const float* __restrict__ blk1_b,
                            float* __restrict__ tp) {
    int u = blockIdx.x * 256 + threadIdx.x;
    if (u >= 2560) return;
    int b = u / 320, rem = u % 320, i = rem >> 6, j = rem & 63;
    float s = fc_c_b[i * 64 + j] + ((i == 0) ? fc_p_b[j] : blk1_b[(i - 1) * 64 + j]);
    #pragma unroll
    for (int k = 0; k < 8; ++k)
        s += partials[(((b * 5 + i) << 3) + k) * 64 + j];
    tp[u] = s;
}

// ---------------------------------------------------------------------------
// One resblock — R4's proven buffer schedule, LDS loads.
// Entry: Ac = cond_i frags, Ab = blk0_i frags (both ready).
// Exit:  Ab = cond_{i+1} (or fco), Ac = blk0_{i+1} (if !last). Caller swaps.
// blk1 accumulates with C=net4 (its bias was folded into tp''_{i+1}).
// ---------------------------------------------------------------------------
__device__ __forceinline__ void rb(half8 (&Ac)[8], half8 (&Ab)[8],
    floatx4 (&net4)[TILES_][4], const half8 (&cB)[TILES_][2], const int (&bt)[TILES_],
    int i, int q, int lane, const _Float16* wl, const float* tp_l, const float* b0_l,
    int next_stage, bool last)
{
    floatx4 bb0[4];
    #pragma unroll
    for (int T = 0; T < 4; ++T)
        bb0[T] = *(const floatx4*)(b0_l + i * 64 + 16 * T + 4 * q);
    // ---- conditioning: net = net + Wc·c + tp'' ----
    #pragma unroll
    for (int t = 0; t < TILES_; ++t) {
        const float* tpb = tp_l + (bt[t] * NB_ + i) * 64 + 4 * q;
        #pragma unroll
        for (int T = 0; T < 4; ++T) {
            floatx4 a = net4[t][T];
            a = __builtin_amdgcn_mfma_f32_16x16x32_f16(Ac[2 * T], cB[t][0], a, 0, 0, 0);
            a = __builtin_amdgcn_mfma_f32_16x16x32_f16(Ac[2 * T + 1], cB[t][1], a, 0, 0, 0);
            net4[t][T] = a + *(const floatx4*)(tpb + 16 * T);
        }
    }
    loadL8(Ac, wl, 10 + i, lane);                   // blk1_i (cond done with Ac)
    // ---- blk0+blk1 fused, ALL 4 tiles before any buffer overwrite ----
    #pragma unroll
    for (int t = 0; t < TILES_; ++t) {
        half8 Bn0 = packB(net4[t][0], net4[t][1]);
        half8 Bn1 = packB(net4[t][2], net4[t][3]);
        floatx4 hh[4];
        #pragma unroll
        for (int T = 0; T < 4; ++T) {
            floatx4 a = bb0[T];
            a = __builtin_amdgcn_mfma_f32_16x16x32_f16(Ab[2 * T], Bn0, a, 0, 0, 0);
            a = __builtin_amdgcn_mfma_f32_16x16x32_f16(Ab[2 * T + 1], Bn1, a, 0, 0, 0);
            hh[T] = a;
        }
        half8 Bh0 = packB(hh[0], hh[1]);
        half8 Bh1 = packB(hh[2], hh[3]);
        #pragma unroll
        for (int T = 0; T < 4; ++T) {
            floatx4 a = net4[t][T];
            a = __builtin_amdgcn_mfma_f32_16x16x32_f16(Ac[2 * T], Bh0, a, 0, 0, 0);
            a = __builtin_amdgcn_mfma_f32_16x16x32_f16(Ac[2 * T + 1], Bh1, a, 0, 0, 0);
            net4[t][T] = a;                          // C=net, bias deferred to tp''_{i+1}
        }
    }
    loadL8(Ab, wl, next_stage, lane);                // cond_{i+1} / fco
    if (!last)
        loadL8(Ac, wl, 5 + i + 1, lane);             // blk0_{i+1}
}

// ---------------------------------------------------------------------------
// Main decoder: 512 threads (8 waves), all weights LDS-resident, 1 block/CU.
// Wave processes one (or two) 4-tile groups of 64 points.
// ---------------------------------------------------------------------------
__global__ __launch_bounds__(THREADS, 1) void decoder_kernel(
    const float* __restrict__ p_g, const float* __restrict__ c_g,
    const float* __restrict__ blk0_b, const float* __restrict__ blk1_b,
    const float* __restrict__ fc_p_W, const float* __restrict__ fc_out_b,
    const _Float16* __restrict__ ws_w, const float* __restrict__ tp_g,
    float* __restrict__ out_g)
{
    extern __shared__ char smem[];
    _Float16* wl   = (_Float16*)(smem + WL_OFF);
    float*    tp_l = (float*)(smem + TPL_OFF);
    float*    b0_l = (float*)(smem + B0L_OFF);
    float*    b14_l= (float*)(smem + B14_OFF);
    float*    fpw_l= (float*)(smem + FPW_OFF);

    const int tid = threadIdx.x, bid = blockIdx.x;

    // ---- stage everything into LDS (once per block) ----
    {
        uint4* dw = (uint4*)wl;
        const uint4* sw = (const uint4*)ws_w;
        for (int u = tid; u < 7808; u += THREADS) dw[u] = sw[u];
        uint4* dt = (uint4*)tp_l;  const uint4* st = (const uint4*)tp_g;
        for (int u = tid; u < 640; u += THREADS) dt[u] = st[u];
        uint4* db = (uint4*)b0_l;  const uint4* sb = (const uint4*)blk0_b;
        for (int u = tid; u < 80; u += THREADS) db[u] = sb[u];
        uint4* d4 = (uint4*)b14_l; const uint4* s4 = (const uint4*)(blk1_b + 4 * 64);
        if (tid < 16) d4[tid] = s4[tid];
        uint4* df = (uint4*)fpw_l; const uint4* sf = (const uint4*)fc_p_W;
        if (tid < 48) df[tid] = sf[tid];
    }
    __syncthreads();

    const int lane = tid & 63;
    const int wv   = tid >> 6;
    const int q    = lane >> 4;
    const int m15  = lane & 15;

    // group assignment: primary group = bid*8+wv; 106 leftover groups spread
    // over blocks bid%7==0 as a second pass on one wave.
    int g_primary = (bid * 8 + wv) * TILES_;        // tile id, 4 tiles
    int npass = 1, g_second = 0;
    if ((bid % 7) == 0) {
        int e = bid / 7;
        if (e < EXTRA && wv == (e & 7)) { npass = 2; g_second = (PRIMARY + e) * TILES_; }
    }

    floatx4 ob = {0.f, 0.f, 0.f, 0.f};
    if (q < 3) ob = *(const floatx4*)(fc_out_b + 4 * q);

    #pragma unroll 1
    for (int pass = 0; pass < npass; ++pass) {
        int g0 = pass ? g_second : g_primary;       // first of 4 tile ids
        int bt[TILES_];
        long pbase[TILES_];
        #pragma unroll
        for (int t = 0; t < TILES_; ++t) {
            int gt = g0 + t;
            int b  = gt / 3125;                     // 3125 tiles per batch
            int lt = gt - b * 3125;
            bt[t] = b;
            pbase[t] = (long)b * N_ + (long)lt * 16;
        }

        // ---- preload stage-0 fragment buffers ----
        half8 X[8], Y[8];
        loadL8(X, wl, 0, lane);                     // cond_0
        loadL8(Y, wl, 5, lane);                     // blk0_0

        // ---- c -> B-operand registers ----
        half8 cB[TILES_][2];
        #pragma unroll
        for (int t = 0; t < TILES_; ++t) {
            const float* cr = c_g + (size_t)(pbase[t] + m15) * 64;
            #pragma unroll
            for (int h = 0; h < 2; ++h) {
                float4 v0 = *(const float4*)(cr + 32 * h + 8 * q);
                float4 v1 = *(const float4*)(cr + 32 * h + 8 * q + 4);
                union { fp16x2 h2[4]; half8 h8; } u;
                u.h2[0] = __builtin_amdgcn_cvt_pkrtz(v0.x, v0.y);
                u.h2[1] = __builtin_amdgcn_cvt_pkrtz(v0.z, v0.w);
                u.h2[2] = __builtin_amdgcn_cvt_pkrtz(v1.x, v1.y);
                u.h2[3] = __builtin_amdgcn_cvt_pkrtz(v1.z, v1.w);
                cB[t][h] = u.h8;
            }
        }

        // ---- net init: p @ fc_p_W (all biases folded into tp''_0) ----
        floatx4 net4[TILES_][4];
        #pragma unroll
        for (int t = 0; t < TILES_; ++t) {
            long g = pbase[t] + m15;
            float pp0 = p_g[g * 3 + 0], pp1 = p_g[g * 3 + 1], pp2 = p_g[g * 3 + 2];
            #pragma unroll
            for (int T = 0; T < 4; ++T) {
                floatx4 w0 = *(const floatx4*)(fpw_l + 16 * T + 4 * q);
                floatx4 w1 = *(const floatx4*)(fpw_l + 64 + 16 * T + 4 * q);
                floatx4 w2 = *(const floatx4*)(fpw_l + 128 + 16 * T + 4 * q);
                net4[t][T] = w0 * pp0 + w1 * pp1 + w2 * pp2;
            }
        }

        // ---- 5 resblocks, alternating fragment buffers ----
        rb(X, Y, net4, cB, bt, 0, q, lane, wl, tp_l, b0_l, 1, false);
        rb(Y, X, net4, cB, bt, 1, q, lane, wl, tp_l, b0_l, 2, false);
        rb(X, Y, net4, cB, bt, 2, q, lane, wl, tp_l, b0_l, 3, false);
        rb(Y, X, net4, cB, bt, 3, q, lane, wl, tp_l, b0_l, 4, false);
        rb(X, Y, net4, cB, bt, 4, q, lane, wl, tp_l, b0_l, 15, true);  // -> fco in Y

        // ---- output: out = relu(net + b1_4) @ fc_out + b ----
        floatx4 b14v[4];
        #pragma unroll
        for (int T = 0; T < 4; ++T)
            b14v[T] = *(const floatx4*)(b14_l + 16 * T + 4 * q);
        #pragma unroll
        for (int t = 0; t < TILES_; ++t) {
            half8 Bn0 = packB(net4[t][0] + b14v[0], net4[t][1] + b14v[1]);
            half8 Bn1 = packB(net4[t][2] + b14v[2], net4[t][3] + b14v[3]);
            floatx4 a = ob;
            a = __builtin_amdgcn_mfma_f32_16x16x32_f16(Y[0], Bn0, a, 0, 0, 0);
            a = __builtin_amdgcn_mfma_f32_16x16x32_f16(Y[1], Bn1, a, 0, 0, 0);
            if (q < 3) {
                long g = pbase[t] + m15;
                *(float4*)(out_g + g * OUT_ + 4 * q) = make_float4(a[0], a[1], a[2], a[3]);
            }
        }
    }
}

// ---------------------------------------------------------------------------
extern "C" void kernel_launch(void* const* d_in, const int* in_sizes, int n_in,
                              void* d_out, int out_size, void* d_ws, size_t ws_size,
                              hipStream_t stream) {
    const float* p        = (const float*)d_in[0];
    const float* c        = (const float*)d_in[1];
    const float* tf       = (const float*)d_in[2];
    const float* fc_p_W   = (const float*)d_in[3];
    const float* fc_p_b   = (const float*)d_in[4];
    const float* fc_c_W   = (const float*)d_in[5];
    const float* fc_c_b   = (const float*)d_in[6];
    const float* blk0_W   = (const float*)d_in[7];
    const float* blk0_b   = (const float*)d_in[8];
    const float* blk1_W   = (const float*)d_in[9];
    const float* blk1_b   = (const float*)d_in[10];
    const float* fc_out_W = (const float*)d_in[11];
    const float* fc_out_b = (const float*)d_in[12];
    float* out = (float*)d_out;

    // ws: ws_w 8192 chunks *16B = 131072 | partials 81920 | tp'' 10240
    _Float16* ws_w  = (_Float16*)d_ws;
    float* partials = (float*)((char*)d_ws + 131072);
    float* tp       = (float*)((char*)d_ws + 131072 + 81920);

    prep_kernel<<<112, 256, 0, stream>>>(fc_c_W, blk0_W, blk1_W, fc_out_W, tf, ws_w, partials);
    finalize_tp<<<10, 256, 0, stream>>>(partials, fc_c_b, fc_p_b, blk1_b, tp);

    (void)hipFuncSetAttribute((const void*)decoder_kernel,
                        hipFuncAttributeMaxDynamicSharedMemorySize, SMEM_BYTES);
    decoder_kernel<<<GRID, THREADS, SMEM_BYTES, stream>>>(
        p, c, blk0_b, blk1_b, fc_p_W, fc_out_b, ws_w, tp, out);
}

// Round 8
// 253.412 us; speedup vs baseline: 2.7838x; 2.7838x over previous
//
#include <hip/hip_runtime.h>

// AblationDecoder: B=8, N=50000, DIM=3, C_DIM=64, TASK_DIM=512, H=64, NB=5, OUT=12
// R8: LDS-resident weights (R7) with spill-free structure: no pass loop, no tail
// masks (6250 waves x exactly 4 tiles), A-fragments loaded per-stage (no cross-
// stage buffers), __launch_bounds__(512,2).
#define B_    8
#define N_    50000
#define NB_   5
#define OUT_  12
#define THREADS 512
#define TILES_ 4
#define NGROUPS 6250          // (8*50000/16)/4 four-tile groups, exact
#define GRID   782            // ceil(6250/8) blocks of 8 waves

// LDS layout (bytes)
#define WL_OFF   0            // 7808 chunks * 16B = 124928 (15 stages + fco)
#define TPL_OFF  124928       // tp''[8][5][64] f32 = 10240
#define B0L_OFF  135168       // blk0_b[5][64] f32 = 1280
#define B14_OFF  136448       // blk1_b[4][64] f32 = 256
#define FPW_OFF  136704       // fc_p_W [3][64] f32 = 768
#define SMEM_BYTES 137472

typedef _Float16 half8  __attribute__((ext_vector_type(8)));
typedef __fp16   fp16x2 __attribute__((ext_vector_type(2)));   // cvt_pkrtz return type
typedef float   floatx4 __attribute__((ext_vector_type(4)));

__device__ __forceinline__ half8 ldl8(const _Float16* p) {
    union { uint4 u; half8 h; } x;
    x.u = *(const uint4*)p;
    return x.h;
}

// relu + pack 8 f32 (two D-layout accs) -> B fragment, via v_cvt_pkrtz
__device__ __forceinline__ half8 packB(floatx4 a, floatx4 b) {
    union { fp16x2 h2[4]; half8 h8; } u;
    u.h2[0] = __builtin_amdgcn_cvt_pkrtz(fmaxf(a[0], 0.f), fmaxf(a[1], 0.f));
    u.h2[1] = __builtin_amdgcn_cvt_pkrtz(fmaxf(a[2], 0.f), fmaxf(a[3], 0.f));
    u.h2[2] = __builtin_amdgcn_cvt_pkrtz(fmaxf(b[0], 0.f), fmaxf(b[1], 0.f));
    u.h2[3] = __builtin_amdgcn_cvt_pkrtz(fmaxf(b[2], 0.f), fmaxf(b[3], 0.f));
    return u.h8;
}

// load one stage's 8 A-fragments from LDS (frag idx = 2T+h)
__device__ __forceinline__ void loadL8(half8 (&A)[8], const _Float16* wl, int stage, int lane) {
    const _Float16* b = wl + (size_t)stage * 512 * 8;
    #pragma unroll
    for (int T = 0; T < 4; ++T)
        #pragma unroll
        for (int h = 0; h < 2; ++h)
            A[2 * T + h] = ldl8(b + (size_t)(T * 128 + h * 64 + lane) * 8);
}

// ---------------------------------------------------------------------------
// Pre-kernel A: blocks 0..31 build f16 A-fragment weights (single copy);
// blocks 32..111 compute task-feature projection partials.
// ws chunk layout (16B chunks): cidx = stage*512 + T*128 + h*64 + q*16 + m15
//   stage: cond_i=i, blk0_i=5+i, blk1_i=10+i, fco=15 (chunks 7680..7807 real)
//   halves j: cond: k=32h+8q+j (natural-k c); blk0/blk1/fco: f=32h+16*(j>>2)+4q+(j&3)
// ---------------------------------------------------------------------------
__global__ void prep_kernel(const float* __restrict__ fc_c_W,
                            const float* __restrict__ blk0_W,
                            const float* __restrict__ blk1_W,
                            const float* __restrict__ fc_out_W,
                            const float* __restrict__ tf,
                            _Float16* __restrict__ ws_w,
                            float* __restrict__ partials) {
    int bid = blockIdx.x, tid = threadIdx.x;
    if (bid < 32) {
        int u = bid * 256 + tid;          // 0..8191
        if (u < 7680) {
            int m15 = u & 15, q = (u >> 4) & 3, h = (u >> 6) & 1, T = (u >> 7) & 3;
            int mi = u >> 9;              // 0..14
            int mat = mi / 5, i = mi % 5;
            int n = T * 16 + m15;
            _Float16 out[8];
            #pragma unroll
            for (int j = 0; j < 8; ++j) {
                float v;
                if (mat == 0) {
                    int k = 32 * h + 8 * q + j;
                    v = fc_c_W[((size_t)i * 576 + k) * 64 + n];
                } else {
                    int f = 32 * h + 16 * (j >> 2) + 4 * q + (j & 3);
                    const float* W = (mat == 1) ? blk0_W : blk1_W;
                    v = W[((size_t)i * 64 + f) * 64 + n];
                }
                out[j] = (_Float16)v;
            }
            *(uint4*)(ws_w + (size_t)u * 8) = *(uint4*)out;
        } else {
            int e = u - 7680;             // 0..511 (only 0..127 meaningful)
            _Float16 out[8] = {};
            if (e < 128) {
                int m15 = e & 15, q = (e >> 4) & 3, h = (e >> 6) & 1;
                #pragma unroll
                for (int j = 0; j < 8; ++j) {
                    int f = 32 * h + 16 * (j >> 2) + 4 * q + (j & 3);
                    out[j] = (m15 < OUT_) ? (_Float16)fc_out_W[f * OUT_ + m15] : (_Float16)0.f;
                }
            }
            *(uint4*)(ws_w + (size_t)u * 8) = *(uint4*)out;
        }
    } else {
        int idx2 = bid - 32;              // 0..79
        int b = idx2 / 10, rem = idx2 % 10, i = rem >> 1, hf = rem & 1;
        int g = tid >> 6, j = tid & 63;
        const float* W  = fc_c_W + ((size_t)i * 576 + 64) * 64;
        const float* tb = tf + b * 512;
        int t0 = hf * 256 + g * 64;
        float acc = 0.f;
        #pragma unroll 8
        for (int t = 0; t < 64; ++t)
            acc += tb[t0 + t] * W[(size_t)(t0 + t) * 64 + j];
        partials[(((b * 5 + i) << 3) + (hf * 4 + g)) * 64 + j] = acc;
    }
}

// Pre-kernel B: tp''[b][i] = Σ partials + fc_c_b[i] + (i==0 ? fc_p_b : blk1_b[i-1])
__global__ void finalize_tp(const float* __restrict__ partials,
                            const float* __restrict__ fc_c_b,
                            const float* __restrict__ fc_p_b,
                            const float* __restrict__ blk1_b,
                            float* __restrict__ tp) {
    int u = blockIdx.x * 256 + threadIdx.x;
    if (u >= 2560) return;
    int b = u / 320, rem = u % 320, i = rem >> 6, j = rem & 63;
    float s = fc_c_b[i * 64 + j] + ((i == 0) ? fc_p_b[j] : blk1_b[(i - 1) * 64 + j]);
    #pragma unroll
    for (int k = 0; k < 8; ++k)
        s += partials[(((b * 5 + i) << 3) + k) * 64 + j];
    tp[u] = s;
}

// ---------------------------------------------------------------------------
// Main decoder: 512 threads (8 waves), all weights LDS-resident, 1 block/CU.
// Wave g handles exactly 4 tiles (tiles 4g..4g+3); no masks, no pass loop.
// ---------------------------------------------------------------------------
__global__ __launch_bounds__(THREADS, 2) void decoder_kernel(
    const float* __restrict__ p_g, const float* __restrict__ c_g,
    const float* __restrict__ blk0_b, const float* __restrict__ blk1_b,
    const float* __restrict__ fc_p_W, const float* __restrict__ fc_out_b,
    const _Float16* __restrict__ ws_w, const float* __restrict__ tp_g,
    float* __restrict__ out_g)
{
    extern __shared__ char smem[];
    _Float16* wl   = (_Float16*)(smem + WL_OFF);
    float*    tp_l = (float*)(smem + TPL_OFF);
    float*    b0_l = (float*)(smem + B0L_OFF);
    float*    b14_l= (float*)(smem + B14_OFF);
    float*    fpw_l= (float*)(smem + FPW_OFF);

    const int tid = threadIdx.x, bid = blockIdx.x;

    // ---- stage everything into LDS (once per block) ----
    {
        uint4* dw = (uint4*)wl;
        const uint4* sw = (const uint4*)ws_w;
        for (int u = tid; u < 7808; u += THREADS) dw[u] = sw[u];
        uint4* dt = (uint4*)tp_l;  const uint4* st = (const uint4*)tp_g;
        for (int u = tid; u < 640; u += THREADS) dt[u] = st[u];
        uint4* db = (uint4*)b0_l;  const uint4* sb = (const uint4*)blk0_b;
        for (int u = tid; u < 80; u += THREADS) db[u] = sb[u];
        uint4* d4 = (uint4*)b14_l; const uint4* s4 = (const uint4*)(blk1_b + 4 * 64);
        if (tid < 16) d4[tid] = s4[tid];
        uint4* df = (uint4*)fpw_l; const uint4* sf = (const uint4*)fc_p_W;
        if (tid < 48) df[tid] = sf[tid];
    }
    __syncthreads();          // only barrier in the kernel

    const int lane = tid & 63;
    const int wv   = tid >> 6;
    const int q    = lane >> 4;
    const int m15  = lane & 15;

    const int g = bid * 8 + wv;
    if (g >= NGROUPS) return;             // after the barrier: safe

    // ---- tile addressing (a group may straddle batches; per-tile batch) ----
    int bt[TILES_];
    long pbase[TILES_];
    #pragma unroll
    for (int t = 0; t < TILES_; ++t) {
        int gt = g * TILES_ + t;
        int b  = gt / 3125;               // 3125 tiles per batch
        int lt = gt - b * 3125;
        bt[t] = b;
        pbase[t] = (long)b * N_ + (long)lt * 16;
    }

    // ---- c -> B-operand registers (held for all 5 resblocks) ----
    half8 cB[TILES_][2];
    #pragma unroll
    for (int t = 0; t < TILES_; ++t) {
        const float* cr = c_g + (size_t)(pbase[t] + m15) * 64;
        #pragma unroll
        for (int h = 0; h < 2; ++h) {
            float4 v0 = *(const float4*)(cr + 32 * h + 8 * q);
            float4 v1 = *(const float4*)(cr + 32 * h + 8 * q + 4);
            union { fp16x2 h2[4]; half8 h8; } u;
            u.h2[0] = __builtin_amdgcn_cvt_pkrtz(v0.x, v0.y);
            u.h2[1] = __builtin_amdgcn_cvt_pkrtz(v0.z, v0.w);
            u.h2[2] = __builtin_amdgcn_cvt_pkrtz(v1.x, v1.y);
            u.h2[3] = __builtin_amdgcn_cvt_pkrtz(v1.z, v1.w);
            cB[t][h] = u.h8;
        }
    }

    // ---- net init: p @ fc_p_W (all biases folded into tp''_0) ----
    floatx4 net4[TILES_][4];
    #pragma unroll
    for (int t = 0; t < TILES_; ++t) {
        long gp = pbase[t] + m15;
        float pp0 = p_g[gp * 3 + 0], pp1 = p_g[gp * 3 + 1], pp2 = p_g[gp * 3 + 2];
        #pragma unroll
        for (int T = 0; T < 4; ++T) {
            floatx4 w0 = *(const floatx4*)(fpw_l + 16 * T + 4 * q);
            floatx4 w1 = *(const floatx4*)(fpw_l + 64 + 16 * T + 4 * q);
            floatx4 w2 = *(const floatx4*)(fpw_l + 128 + 16 * T + 4 * q);
            net4[t][T] = w0 * pp0 + w1 * pp1 + w2 * pp2;
        }
    }

    // ---- 5 resblocks; A-fragments loaded from LDS per stage ----
    #pragma unroll 1
    for (int i = 0; i < NB_; ++i) {
        half8 Ax[8], Ay[8];
        loadL8(Ax, wl, i, lane);          // cond_i
        loadL8(Ay, wl, 5 + i, lane);      // blk0_i (issued together with cond)
        floatx4 bb0[4];
        #pragma unroll
        for (int T = 0; T < 4; ++T)
            bb0[T] = *(const floatx4*)(b0_l + i * 64 + 16 * T + 4 * q);
        // conditioning: net = net + Wc·c + tp''
        #pragma unroll
        for (int t = 0; t < TILES_; ++t) {
            const float* tpb = tp_l + (bt[t] * NB_ + i) * 64 + 4 * q;
            #pragma unroll
            for (int T = 0; T < 4; ++T) {
                floatx4 a = net4[t][T];
                a = __builtin_amdgcn_mfma_f32_16x16x32_f16(Ax[2 * T], cB[t][0], a, 0, 0, 0);
                a = __builtin_amdgcn_mfma_f32_16x16x32_f16(Ax[2 * T + 1], cB[t][1], a, 0, 0, 0);
                net4[t][T] = a + *(const floatx4*)(tpb + 16 * T);
            }
        }
        loadL8(Ax, wl, 10 + i, lane);     // blk1_i (cond is done with Ax)
        // blk0+blk1 fused per tile; blk1 C=net (bias folded into tp''_{i+1})
        #pragma unroll
        for (int t = 0; t < TILES_; ++t) {
            half8 Bn0 = packB(net4[t][0], net4[t][1]);
            half8 Bn1 = packB(net4[t][2], net4[t][3]);
            floatx4 hh[4];
            #pragma unroll
            for (int T = 0; T < 4; ++T) {
                floatx4 a = bb0[T];
                a = __builtin_amdgcn_mfma_f32_16x16x32_f16(Ay[2 * T], Bn0, a, 0, 0, 0);
                a = __builtin_amdgcn_mfma_f32_16x16x32_f16(Ay[2 * T + 1], Bn1, a, 0, 0, 0);
                hh[T] = a;
            }
            half8 Bh0 = packB(hh[0], hh[1]);
            half8 Bh1 = packB(hh[2], hh[3]);
            #pragma unroll
            for (int T = 0; T < 4; ++T) {
                floatx4 a = net4[t][T];
                a = __builtin_amdgcn_mfma_f32_16x16x32_f16(Ax[2 * T], Bh0, a, 0, 0, 0);
                a = __builtin_amdgcn_mfma_f32_16x16x32_f16(Ax[2 * T + 1], Bh1, a, 0, 0, 0);
                net4[t][T] = a;
            }
        }
    }

    // ---- output: out = relu(net + b1_4) @ fc_out + b ----
    half8 Ao0 = ldl8(wl + (size_t)(15 * 512 + 0 * 64 + q * 16 + m15) * 8);
    half8 Ao1 = ldl8(wl + (size_t)(15 * 512 + 1 * 64 + q * 16 + m15) * 8);
    floatx4 b14v[4];
    #pragma unroll
    for (int T = 0; T < 4; ++T)
        b14v[T] = *(const floatx4*)(b14_l + 16 * T + 4 * q);
    floatx4 ob = {0.f, 0.f, 0.f, 0.f};
    if (q < 3) ob = *(const floatx4*)(fc_out_b + 4 * q);
    #pragma unroll
    for (int t = 0; t < TILES_; ++t) {
        half8 Bn0 = packB(net4[t][0] + b14v[0], net4[t][1] + b14v[1]);
        half8 Bn1 = packB(net4[t][2] + b14v[2], net4[t][3] + b14v[3]);
        floatx4 a = ob;
        a = __builtin_amdgcn_mfma_f32_16x16x32_f16(Ao0, Bn0, a, 0, 0, 0);
        a = __builtin_amdgcn_mfma_f32_16x16x32_f16(Ao1, Bn1, a, 0, 0, 0);
        if (q < 3) {
            long gp = pbase[t] + m15;
            *(float4*)(out_g + gp * OUT_ + 4 * q) = make_float4(a[0], a[1], a[2], a[3]);
        }
    }
}

// ---------------------------------------------------------------------------
extern "C" void kernel_launch(void* const* d_in, const int* in_sizes, int n_in,
                              void* d_out, int out_size, void* d_ws, size_t ws_size,
                              hipStream_t stream) {
    const float* p        = (const float*)d_in[0];
    const float* c        = (const float*)d_in[1];
    const float* tf       = (const float*)d_in[2];
    const float* fc_p_W   = (const float*)d_in[3];
    const float* fc_p_b   = (const float*)d_in[4];
    const float* fc_c_W   = (const float*)d_in[5];
    const float* fc_c_b   = (const float*)d_in[6];
    const float* blk0_W   = (const float*)d_in[7];
    const float* blk0_b   = (const float*)d_in[8];
    const float* blk1_W   = (const float*)d_in[9];
    const float* blk1_b   = (const float*)d_in[10];
    const float* fc_out_W = (const float*)d_in[11];
    const float* fc_out_b = (const float*)d_in[12];
    float* out = (float*)d_out;

    // ws: ws_w 8192 chunks *16B = 131072 | partials 81920 | tp'' 10240
    _Float16* ws_w  = (_Float16*)d_ws;
    float* partials = (float*)((char*)d_ws + 131072);
    float* tp       = (float*)((char*)d_ws + 131072 + 81920);

    prep_kernel<<<112, 256, 0, stream>>>(fc_c_W, blk0_W, blk1_W, fc_out_W, tf, ws_w, partials);
    finalize_tp<<<10, 256, 0, stream>>>(partials, fc_c_b, fc_p_b, blk1_b, tp);

    (void)hipFuncSetAttribute((const void*)decoder_kernel,
                        hipFuncAttributeMaxDynamicSharedMemorySize, SMEM_BYTES);
    decoder_kernel<<<GRID, THREADS, SMEM_BYTES, stream>>>(
        p, c, blk0_b, blk1_b, fc_p_W, fc_out_b, ws_w, tp, out);
}